// Round 4
// baseline (115.578 us; speedup 1.0000x reference)
//
#include <hip/hip_runtime.h>
#include <math.h>

#define BATCH 512    // post-reshape scan lanes
#define FRAGS 256    // fragments per chain
#define GROUP 16     // fragments per scan group == frags per block
#define NGRP  (FRAGS/GROUP)   // 16 groups
#define BTILE 32     // batch lanes per block
#define NTILE (BATCH/BTILE)   // 16 b-tiles
#define RPF   8      // residues per fragment (L=2048)
#define NPTS  (3*RPF)         // 24 points per fragment
#define READY 0x5EADBEEF

// Rigid transform: 12 floats, R row-major r[i*3+j], t=[9..11]. x' = Rx + t.
// compose(A,B): A is the EARLIER prefix, B the later. (Verified R5-R9.)
__device__ __forceinline__ void compose(const float* A, const float* B, float* D) {
    float d[12];
    #pragma unroll
    for (int i = 0; i < 3; ++i) {
        #pragma unroll
        for (int j = 0; j < 3; ++j)
            d[i*3+j] = A[i*3+0]*B[0*3+j] + A[i*3+1]*B[1*3+j] + A[i*3+2]*B[2*3+j];
        d[9+i] = A[i*3+0]*B[9] + A[i*3+1]*B[10] + A[i*3+2]*B[11] + A[9+i];
    }
    #pragma unroll
    for (int k = 0; k < 12; ++k) D[k] = d[k];
}

__device__ __forceinline__ void set_identity(float* D) {
    D[0]=1.f; D[1]=0.f; D[2]=0.f;
    D[3]=0.f; D[4]=1.f; D[5]=0.f;
    D[6]=0.f; D[7]=0.f; D[8]=1.f;
    D[9]=0.f; D[10]=0.f; D[11]=0.f;
}

__device__ __forceinline__ void frame_of(
    float ax, float ay, float az,
    float bx, float by, float bz,
    float cx, float cy, float cz,
    float* out /*12*/)
{
    float bcx = cx - bx, bcy = cy - by, bcz = cz - bz;
    float inv = rsqrtf(bcx*bcx + bcy*bcy + bcz*bcz + 1e-12f);
    bcx *= inv; bcy *= inv; bcz *= inv;
    float bax = bx - ax, bay = by - ay, baz = bz - az;
    float nx = bay*bcz - baz*bcy;
    float ny = baz*bcx - bax*bcz;
    float nz = bax*bcy - bay*bcx;
    inv = rsqrtf(nx*nx + ny*ny + nz*nz + 1e-12f);
    nx *= inv; ny *= inv; nz *= inv;
    float mx = ny*bcz - nz*bcy;
    float my = nz*bcx - nx*bcz;
    float mz = nx*bcy - ny*bcx;
    out[0] = bcx; out[1] = mx; out[2] = nx;
    out[3] = bcy; out[4] = my; out[5] = ny;
    out[6] = bcz; out[7] = mz; out[8] = nz;
    out[9] = cx; out[10] = cy; out[11] = cz;
}

__device__ __forceinline__ void nerf_step(
    float ax, float ay, float az,
    float bx, float by, float bz,
    float cx, float cy, float cz,
    float px, float py, float pz,
    float& ox, float& oy, float& oz)
{
    float bcx = cx - bx, bcy = cy - by, bcz = cz - bz;
    float inv = rsqrtf(bcx*bcx + bcy*bcy + bcz*bcz + 1e-12f);
    bcx *= inv; bcy *= inv; bcz *= inv;
    float bax = bx - ax, bay = by - ay, baz = bz - az;
    float nx = bay*bcz - baz*bcy;
    float ny = baz*bcx - bax*bcz;
    float nz = bax*bcy - bay*bcx;
    inv = rsqrtf(nx*nx + ny*ny + nz*nz + 1e-12f);
    nx *= inv; ny *= inv; nz *= inv;
    float mx = ny*bcz - nz*bcy;
    float my = nz*bcx - nx*bcz;
    float mz = nx*bcy - ny*bcx;
    ox = bcx*px + mx*py + nx*pz + cx;
    oy = bcy*px + my*py + ny*pz + cy;
    oz = bcz*px + mz*py + nz*pz + cz;
}

// Per-lane permuted bond constants. Reshape (L,B,3,3)->(3L,B,3) makes scan
// lane b at residue l, step k consume dih flat[l*1536 + 512k + b]; bond-const
// index = (512k+b)%3 -> pattern d = {b%3, (b+2)%3, (b+1)%3}. (Verified R5.)
__device__ __forceinline__ void lane_consts(int b, float* rcl, float* rsl) {
    const float PI = 3.14159265358979323846f;
    float rc[3], rs[3];
    rc[0] = 145.801f * cosf(PI - 2.124f); rs[0] = 145.801f * sinf(PI - 2.124f);
    rc[1] = 152.326f * cosf(PI - 1.941f); rs[1] = 152.326f * sinf(PI - 1.941f);
    rc[2] = 132.868f * cosf(PI - 2.028f); rs[2] = 132.868f * sinf(PI - 2.028f);
    const int d0 = b % 3, d1 = (b + 2) % 3, d2 = (b + 1) % 3;
    rcl[0] = rc[d0]; rcl[1] = rc[d1]; rcl[2] = rc[d2];
    rsl[0] = rs[d0]; rsl[1] = rs[d1]; rsl[2] = rs[d2];
}

// Single-dispatch grid scan via flag lookback (no cooperative launch — R8
// showed hipLaunchCooperativeKernel no-ops under graph capture).
// Block = (g, btile): GROUP frags x BTILE b-lanes = 512 threads. All 256
// blocks co-resident (1/CU, LDS 53KB) -> spin-wait cannot deadlock. Flags
// poisoned 0xAA before every launch (!= READY), so they self-reset.
//
// R13 theory (post-mortem R12: VGPR stayed 80 despite launch_bounds; kernel
// still latency-stalled at VALUBusy 15%): can't out-argue the allocator, so
// SHRINK THE LIVE SET. The 72-float lx/ly/lz array (points held across both
// scans) was the scratch driver. The NeRF recursion is rigid-motion-
// equivariant (differences + cross products + normalization only), so the
// tail RECOMPUTES the chain starting from the G-transformed init triple and
// emits global points directly: no point array, no per-point mat-vec, dd[]
// (24 regs) is the only state carried across the scans. Extra chain pass
// ~1500 VALU insts (~1.3us issue) vs ~35us of suspected spill stalls.
__global__ void __launch_bounds__(GROUP * BTILE, 2) coord_onepass(
    const float* __restrict__ dih, float* __restrict__ T,
    int* __restrict__ flags, float* __restrict__ out)
{
    const int btile = blockIdx.x & (NTILE - 1);
    const int g     = blockIdx.x >> 4;                 // NTILE==16
    const int bsub  = threadIdx.x & (BTILE - 1);
    const int j     = threadIdx.x >> 5;                // BTILE==32
    const int f     = g * GROUP + j;
    const int b     = btile * BTILE + bsub;

    __shared__ float BufA[GROUP * BTILE * 13];         // stride 13: conflict-free
    __shared__ float BufB[GROUP * BTILE * 13];
    float* rowA = &BufA[(size_t)threadIdx.x * 13];
    float* rowB = &BufB[(size_t)threadIdx.x * 13];

    float rcl[3], rsl[3];
    lane_consts(b, rcl, rsl);

    // ---- Load this fragment's dihedrals once; lives in regs through the
    //      scans and feeds both chain passes ----
    float dd[NPTS];
    #pragma unroll
    for (int r = 0; r < RPF; ++r) {
        const float* src = dih + (size_t)(f * RPF + r) * (3 * BATCH) + b;
        dd[r*3 + 0] = src[0];
        dd[r*3 + 1] = src[BATCH];
        dd[r*3 + 2] = src[2 * BATCH];
    }

    // ---- Pass 1: local chain, NO point storage — only the end frame ----
    float ax = -0.70710678118654752f, ay = 1.22474487139158905f, az = 0.0f;
    float bx = -1.41421356237309505f, by = 0.0f, bz = 0.0f;
    float cx = 0.0f, cy = 0.0f, cz = 0.0f;

    #pragma unroll
    for (int q = 0; q < NPTS; ++q) {
        float sn, cs;
        __sincosf(dd[q], &sn, &cs);
        const int k = q - (q / 3) * 3;                 // q % 3 (unrolled-const)
        float ox, oy, oz;
        nerf_step(ax, ay, az, bx, by, bz, cx, cy, cz,
                  rcl[k], cs * rsl[k], sn * rsl[k], ox, oy, oz);
        ax = bx; ay = by; az = bz;
        bx = cx; by = cy; bz = cz;
        cx = ox; cy = oy; cz = oz;
    }

    float h[12];                         // this fragment's local frame
    frame_of(ax, ay, az, bx, by, bz, cx, cy, cz, h);

    // ---- Scan 1: EXCLUSIVE Hillis-Steele over j (16 rows, 5 rounds).
    //      cur ends as E_j = h_0 o ... o h_{j-1} == P[j-1]; publisher row
    //      composes cur o h for the group total. Ping-pong A/B: one barrier
    //      per round, WAR-safe. ----
    #pragma unroll
    for (int k = 0; k < 12; ++k) rowA[k] = h[k];
    __syncthreads();
    float cur[12];
    if (j == 0) set_identity(cur);
    else {
        #pragma unroll
        for (int k = 0; k < 12; ++k)
            cur[k] = BufA[(size_t)(threadIdx.x - BTILE) * 13 + k];
    }

    #pragma unroll
    for (int k = 0; k < 12; ++k) rowB[k] = cur[k];
    __syncthreads();
    if (j >= 1) compose(&BufB[(size_t)(threadIdx.x - 1*BTILE) * 13], cur, cur);

    #pragma unroll
    for (int k = 0; k < 12; ++k) rowA[k] = cur[k];
    __syncthreads();
    if (j >= 2) compose(&BufA[(size_t)(threadIdx.x - 2*BTILE) * 13], cur, cur);

    #pragma unroll
    for (int k = 0; k < 12; ++k) rowB[k] = cur[k];
    __syncthreads();
    if (j >= 4) compose(&BufB[(size_t)(threadIdx.x - 4*BTILE) * 13], cur, cur);

    #pragma unroll
    for (int k = 0; k < 12; ++k) rowA[k] = cur[k];
    __syncthreads();
    if (j >= 8) compose(&BufA[(size_t)(threadIdx.x - 8*BTILE) * 13], cur, cur);

    // ---- Publish group total T_g = cur o h (row 15), wave-level release.
    //      j==15 rows are lanes 32..63 of wave 7; the release store's
    //      wave-wide s_waitcnt vmcnt(0) orders sibling lanes' T stores
    //      before the flag becomes visible. Last group's total is dead. ----
    if (j == GROUP - 1 && g < NGRP - 1) {
        float tg[12];
        compose(cur, h, tg);
        #pragma unroll
        for (int k = 0; k < 12; ++k)
            __hip_atomic_store(&T[((size_t)g * 12 + k) * BATCH + b], tg[k],
                               __ATOMIC_RELAXED, __HIP_MEMORY_SCOPE_AGENT);
        if (bsub == 0)
            __hip_atomic_store(&flags[g * NTILE + btile], READY,
                               __ATOMIC_RELEASE, __HIP_MEMORY_SCOPE_AGENT);
    }

    // ---- Scan 2 (g>0 only; uniform branch): parallel exclusive-prefix of
    //      the group totals. Row j holds T_j (j<g) else identity; 4 rounds;
    //      broadcast row g-1 -> E_g. ----
    float G[12];
    if (g == 0) {
        #pragma unroll
        for (int k = 0; k < 12; ++k) G[k] = cur[k];    // E=I: G = P[j-1]
    } else {
        float cur2[12];
        if (j < g) {
            while (__hip_atomic_load(&flags[j * NTILE + btile],
                                     __ATOMIC_ACQUIRE, __HIP_MEMORY_SCOPE_AGENT)
                   != READY) {
                __builtin_amdgcn_s_sleep(1);
            }
            #pragma unroll
            for (int k = 0; k < 12; ++k)
                cur2[k] = __hip_atomic_load(&T[((size_t)j * 12 + k) * BATCH + b],
                                            __ATOMIC_RELAXED, __HIP_MEMORY_SCOPE_AGENT);
        } else {
            set_identity(cur2);
        }

        #pragma unroll
        for (int k = 0; k < 12; ++k) rowB[k] = cur2[k];
        __syncthreads();
        if (j >= 1) compose(&BufB[(size_t)(threadIdx.x - 1*BTILE) * 13], cur2, cur2);

        #pragma unroll
        for (int k = 0; k < 12; ++k) rowA[k] = cur2[k];
        __syncthreads();
        if (j >= 2) compose(&BufA[(size_t)(threadIdx.x - 2*BTILE) * 13], cur2, cur2);

        #pragma unroll
        for (int k = 0; k < 12; ++k) rowB[k] = cur2[k];
        __syncthreads();
        if (j >= 4) compose(&BufB[(size_t)(threadIdx.x - 4*BTILE) * 13], cur2, cur2);

        #pragma unroll
        for (int k = 0; k < 12; ++k) rowA[k] = cur2[k];
        __syncthreads();
        if (j >= 8) compose(&BufA[(size_t)(threadIdx.x - 8*BTILE) * 13], cur2, cur2);

        // broadcast row g-1 (same-address LDS reads across j: free broadcast)
        #pragma unroll
        for (int k = 0; k < 12; ++k) rowB[k] = cur2[k];
        __syncthreads();
        float E[12];
        #pragma unroll
        for (int k = 0; k < 12; ++k)
            E[k] = BufB[(size_t)((g - 1) * BTILE + bsub) * 13 + k];

        compose(E, cur, G);                            // cur = P[j-1] (I at j==0)
    }

    // ---- Pass 2: rerun the chain from the G-transformed init triple; the
    //      recursion's equivariance makes every emitted point global. ----
    {
        const float a0x = -0.70710678118654752f, a0y = 1.22474487139158905f;
        const float b0x = -1.41421356237309505f;
        // init z-components are all 0
        ax = G[0]*a0x + G[1]*a0y + G[9];
        ay = G[3]*a0x + G[4]*a0y + G[10];
        az = G[6]*a0x + G[7]*a0y + G[11];
        bx = G[0]*b0x + G[9];
        by = G[3]*b0x + G[10];
        bz = G[6]*b0x + G[11];
        cx = G[9]; cy = G[10]; cz = G[11];
    }

    struct F3 { float x, y, z; };
    #pragma unroll
    for (int q = 0; q < NPTS; ++q) {
        float sn, cs;
        __sincosf(dd[q], &sn, &cs);
        const int k = q - (q / 3) * 3;                 // q % 3 (unrolled-const)
        float ox, oy, oz;
        nerf_step(ax, ay, az, bx, by, bz, cx, cy, cz,
                  rcl[k], cs * rsl[k], sn * rsl[k], ox, oy, oz);
        ax = bx; ay = by; az = bz;
        bx = cx; by = cy; bz = cz;
        cx = ox; cy = oy; cz = oz;
        size_t n = (size_t)f * NPTS + q;               // scan step index
        float* dst = out + (n * BATCH + b) * 3;
        *reinterpret_cast<F3*>(dst) = F3{ox, oy, oz};
    }
}

extern "C" void kernel_launch(void* const* d_in, const int* in_sizes, int n_in,
                              void* d_out, int out_size, void* d_ws, size_t ws_size,
                              hipStream_t stream) {
    const float* dih = (const float*)d_in[0];
    float* out = (float*)d_out;
    float* T = (float*)d_ws;                           // NGRP*12*BATCH floats
    int* flags = (int*)(T + (size_t)NGRP * 12 * BATCH); // NGRP*NTILE ints

    coord_onepass<<<dim3(NGRP * NTILE), dim3(GROUP * BTILE), 0, stream>>>(
        dih, T, flags, out);
    (void)ws_size; (void)n_in; (void)out_size; (void)in_sizes;
}

// Round 5
// 96.318 us; speedup vs baseline: 1.2000x; 1.2000x over previous
//
#include <hip/hip_runtime.h>
#include <math.h>

#define BATCH 512    // post-reshape scan lanes
#define FRAGS 256    // fragments per chain
#define GROUP 16     // fragments per scan group == frags per block
#define NGRP  (FRAGS/GROUP)   // 16 groups
#define BTILE 32     // batch lanes per block
#define NTILE (BATCH/BTILE)   // 16 b-tiles
#define RPF   8      // residues per fragment (L=2048)
#define READY 0x5EADBEEF

// Rigid transform: 12 floats, R row-major r[i*3+j], t=[9..11]. x' = Rx + t.
// compose(A,B): A is the EARLIER prefix, B the later. (Verified R5-R9.)
__device__ __forceinline__ void compose(const float* A, const float* B, float* D) {
    float d[12];
    #pragma unroll
    for (int i = 0; i < 3; ++i) {
        #pragma unroll
        for (int j = 0; j < 3; ++j)
            d[i*3+j] = A[i*3+0]*B[0*3+j] + A[i*3+1]*B[1*3+j] + A[i*3+2]*B[2*3+j];
        d[9+i] = A[i*3+0]*B[9] + A[i*3+1]*B[10] + A[i*3+2]*B[11] + A[9+i];
    }
    #pragma unroll
    for (int k = 0; k < 12; ++k) D[k] = d[k];
}

__device__ __forceinline__ void set_identity(float* D) {
    D[0]=1.f; D[1]=0.f; D[2]=0.f;
    D[3]=0.f; D[4]=1.f; D[5]=0.f;
    D[6]=0.f; D[7]=0.f; D[8]=1.f;
    D[9]=0.f; D[10]=0.f; D[11]=0.f;
}

__device__ __forceinline__ void frame_of(
    float ax, float ay, float az,
    float bx, float by, float bz,
    float cx, float cy, float cz,
    float* out /*12*/)
{
    float bcx = cx - bx, bcy = cy - by, bcz = cz - bz;
    float inv = rsqrtf(bcx*bcx + bcy*bcy + bcz*bcz + 1e-12f);
    bcx *= inv; bcy *= inv; bcz *= inv;
    float bax = bx - ax, bay = by - ay, baz = bz - az;
    float nx = bay*bcz - baz*bcy;
    float ny = baz*bcx - bax*bcz;
    float nz = bax*bcy - bay*bcx;
    inv = rsqrtf(nx*nx + ny*ny + nz*nz + 1e-12f);
    nx *= inv; ny *= inv; nz *= inv;
    float mx = ny*bcz - nz*bcy;
    float my = nz*bcx - nx*bcz;
    float mz = nx*bcy - ny*bcx;
    out[0] = bcx; out[1] = mx; out[2] = nx;
    out[3] = bcy; out[4] = my; out[5] = ny;
    out[6] = bcz; out[7] = mz; out[8] = nz;
    out[9] = cx; out[10] = cy; out[11] = cz;
}

__device__ __forceinline__ void nerf_step(
    float ax, float ay, float az,
    float bx, float by, float bz,
    float cx, float cy, float cz,
    float px, float py, float pz,
    float& ox, float& oy, float& oz)
{
    float bcx = cx - bx, bcy = cy - by, bcz = cz - bz;
    float inv = rsqrtf(bcx*bcx + bcy*bcy + bcz*bcz + 1e-12f);
    bcx *= inv; bcy *= inv; bcz *= inv;
    float bax = bx - ax, bay = by - ay, baz = bz - az;
    float nx = bay*bcz - baz*bcy;
    float ny = baz*bcx - bax*bcz;
    float nz = bax*bcy - bay*bcx;
    inv = rsqrtf(nx*nx + ny*ny + nz*nz + 1e-12f);
    nx *= inv; ny *= inv; nz *= inv;
    float mx = ny*bcz - nz*bcy;
    float my = nz*bcx - nx*bcz;
    float mz = nx*bcy - ny*bcx;
    ox = bcx*px + mx*py + nx*pz + cx;
    oy = bcy*px + my*py + ny*pz + cy;
    oz = bcz*px + mz*py + nz*pz + cz;
}

// Per-lane permuted bond constants. Reshape (L,B,3,3)->(3L,B,3) makes scan
// lane b at residue l, step k consume dih flat[l*1536 + 512k + b]; bond-const
// index = (512k+b)%3 -> pattern d = {b%3, (b+2)%3, (b+1)%3}. (Verified R5.)
__device__ __forceinline__ void lane_consts(int b, float* rcl, float* rsl) {
    const float PI = 3.14159265358979323846f;
    float rc[3], rs[3];
    rc[0] = 145.801f * cosf(PI - 2.124f); rs[0] = 145.801f * sinf(PI - 2.124f);
    rc[1] = 152.326f * cosf(PI - 1.941f); rs[1] = 152.326f * sinf(PI - 1.941f);
    rc[2] = 132.868f * cosf(PI - 2.028f); rs[2] = 132.868f * sinf(PI - 2.028f);
    const int d0 = b % 3, d1 = (b + 2) % 3, d2 = (b + 1) % 3;
    rcl[0] = rc[d0]; rcl[1] = rc[d1]; rcl[2] = rc[d2];
    rsl[0] = rs[d0]; rsl[1] = rs[d1]; rsl[2] = rs[d2];
}

// Single-dispatch grid scan via flag lookback (no cooperative launch — R8
// showed hipLaunchCooperativeKernel no-ops under graph capture).
// Block = (g, btile): GROUP frags x BTILE b-lanes. All 256 blocks co-resident
// (1/CU) -> spin-wait cannot deadlock. Flags live in d_ws (poisoned 0xAA
// before every launch, != READY, so they self-reset).
//
// R14 theory (post-mortem R11-R13: a ~40us stall floor invariant under all
// compute-structure changes; VALUBusy 15-23%, HBM 10%): the agent-scope
// ACQUIRE spin loop emits global_load + s_waitcnt vmcnt(0) + cache-inv PER
// ITERATION. Hundreds of spinning waves = device-wide invalidation storm.
// Fix: spin on RELAXED loads; ONE acquire fence after the flag is observed,
// before the (relaxed) T loads. Everything else reverted to the fastest
// measured structure (R10/43.9us): points-in-regs, NT hints, inclusive
// scan1 + pprev, parallel scan2, wave-level release, plain launch_bounds.
__global__ void __launch_bounds__(GROUP * BTILE) coord_onepass(
    const float* __restrict__ dih, float* __restrict__ T,
    int* __restrict__ flags, float* __restrict__ out)
{
    const int btile = blockIdx.x & (NTILE - 1);
    const int g     = blockIdx.x >> 4;                 // NTILE==16
    const int bsub  = threadIdx.x & (BTILE - 1);
    const int j     = threadIdx.x >> 5;                // BTILE==32
    const int f     = g * GROUP + j;
    const int b     = btile * BTILE + bsub;

    __shared__ float BufA[GROUP * BTILE * 13];         // stride 13: conflict-free
    __shared__ float BufB[GROUP * BTILE * 13];
    float* rowA = &BufA[(size_t)threadIdx.x * 13];
    float* rowB = &BufB[(size_t)threadIdx.x * 13];

    float rcl[3], rsl[3];
    lane_consts(b, rcl, rsl);

    // ---- Prefetch all dihedrals for this fragment (keeps HBM latency out
    //      of the serial NeRF dependency chain) ----
    float dd[3 * RPF];
    #pragma unroll
    for (int r = 0; r < RPF; ++r) {
        const float* src = dih + (size_t)(f * RPF + r) * (3 * BATCH) + b;
        dd[r*3 + 0] = __builtin_nontemporal_load(src);
        dd[r*3 + 1] = __builtin_nontemporal_load(src + BATCH);
        dd[r*3 + 2] = __builtin_nontemporal_load(src + 2 * BATCH);
    }

    // ---- Stage 1: local chain, points kept in registers ----
    float lx[3 * RPF], ly[3 * RPF], lz[3 * RPF];

    float ax = -0.70710678118654752f, ay = 1.22474487139158905f, az = 0.0f;
    float bx = -1.41421356237309505f, by = 0.0f, bz = 0.0f;
    float cx = 0.0f, cy = 0.0f, cz = 0.0f;

    #pragma unroll
    for (int r = 0; r < RPF; ++r) {
        #pragma unroll
        for (int k = 0; k < 3; ++k) {
            float sn, cs;
            __sincosf(dd[r*3 + k], &sn, &cs);
            float ox, oy, oz;
            nerf_step(ax, ay, az, bx, by, bz, cx, cy, cz,
                      rcl[k], cs * rsl[k], sn * rsl[k], ox, oy, oz);
            ax = bx; ay = by; az = bz;
            bx = cx; by = cy; bz = cz;
            cx = ox; cy = oy; cz = oz;
            lx[r*3 + k] = ox; ly[r*3 + k] = oy; lz[r*3 + k] = oz;
        }
    }

    float cur[12];                       // running inclusive prefix (regs)
    frame_of(ax, ay, az, bx, by, bz, cx, cy, cz, cur);

    // ---- Scan 1: in-block Hillis-Steele over j, register-tracked,
    //      ping-pong A/B (one barrier per round; WAR-safe: each buffer's
    //      readers finish before the next round's barrier) ----
    #pragma unroll
    for (int k = 0; k < 12; ++k) rowA[k] = cur[k];
    __syncthreads();
    if (j >= 1) compose(&BufA[(size_t)(threadIdx.x - 1*BTILE) * 13], cur, cur);

    #pragma unroll
    for (int k = 0; k < 12; ++k) rowB[k] = cur[k];
    __syncthreads();
    if (j >= 2) compose(&BufB[(size_t)(threadIdx.x - 2*BTILE) * 13], cur, cur);

    #pragma unroll
    for (int k = 0; k < 12; ++k) rowA[k] = cur[k];
    __syncthreads();
    if (j >= 4) compose(&BufA[(size_t)(threadIdx.x - 4*BTILE) * 13], cur, cur);

    #pragma unroll
    for (int k = 0; k < 12; ++k) rowB[k] = cur[k];
    __syncthreads();
    if (j >= 8) compose(&BufB[(size_t)(threadIdx.x - 8*BTILE) * 13], cur, cur);

    // final publish of inclusive prefixes -> A
    #pragma unroll
    for (int k = 0; k < 12; ++k) rowA[k] = cur[k];
    __syncthreads();

    // P[f-1] for this thread (row j-1), grabbed before A is reused by scan2
    float pprev[12];
    if (j > 0) {
        #pragma unroll
        for (int k = 0; k < 12; ++k)
            pprev[k] = BufA[(size_t)(threadIdx.x - BTILE) * 13 + k];
    }

    // ---- Publish group total T_g + flag, wave-level release.
    //      j==15 lanes are lanes 32..63 of wave 7; the release store's
    //      wave-wide s_waitcnt vmcnt(0) orders all sibling lanes' T stores
    //      before the flag becomes visible. Last group's total is dead. ----
    if (j == GROUP - 1 && g < NGRP - 1) {
        #pragma unroll
        for (int k = 0; k < 12; ++k)
            __hip_atomic_store(&T[((size_t)g * 12 + k) * BATCH + b], cur[k],
                               __ATOMIC_RELAXED, __HIP_MEMORY_SCOPE_AGENT);
        if (bsub == 0)
            __hip_atomic_store(&flags[g * NTILE + btile], READY,
                               __ATOMIC_RELEASE, __HIP_MEMORY_SCOPE_AGENT);
    }

    // ---- Exclusive global prefix E_g = T_0 o ... o T_{g-1}, then
    //      G = E_g o P[j-1], via a parallel scan over group totals.
    //      R14: spin on RELAXED loads (no per-iteration cache-inv/vmcnt
    //      drain); ONE acquire fence after the flag is seen orders the
    //      subsequent relaxed T loads. ----
    float G[12];
    if (g == 0) {
        if (j == 0) set_identity(G);
        else {
            #pragma unroll
            for (int k = 0; k < 12; ++k) G[k] = pprev[k];
        }
    } else {
        float cur2[12];
        if (j < g) {
            // per-row spin: row j only needs group j's flag
            while (__hip_atomic_load(&flags[j * NTILE + btile],
                                     __ATOMIC_RELAXED, __HIP_MEMORY_SCOPE_AGENT)
                   != READY) {
                __builtin_amdgcn_s_sleep(1);
            }
            __builtin_amdgcn_fence(__ATOMIC_ACQUIRE, "agent");
            #pragma unroll
            for (int k = 0; k < 12; ++k)
                cur2[k] = __hip_atomic_load(&T[((size_t)j * 12 + k) * BATCH + b],
                                            __ATOMIC_RELAXED, __HIP_MEMORY_SCOPE_AGENT);
        } else {
            set_identity(cur2);
        }

        // ping-pong rounds: B, A, B, A (A's final-prefix data was consumed
        // into pprev before any thread can pass the first barrier below)
        #pragma unroll
        for (int k = 0; k < 12; ++k) rowB[k] = cur2[k];
        __syncthreads();
        if (j >= 1) compose(&BufB[(size_t)(threadIdx.x - 1*BTILE) * 13], cur2, cur2);

        #pragma unroll
        for (int k = 0; k < 12; ++k) rowA[k] = cur2[k];
        __syncthreads();
        if (j >= 2) compose(&BufA[(size_t)(threadIdx.x - 2*BTILE) * 13], cur2, cur2);

        #pragma unroll
        for (int k = 0; k < 12; ++k) rowB[k] = cur2[k];
        __syncthreads();
        if (j >= 4) compose(&BufB[(size_t)(threadIdx.x - 4*BTILE) * 13], cur2, cur2);

        #pragma unroll
        for (int k = 0; k < 12; ++k) rowA[k] = cur2[k];
        __syncthreads();
        if (j >= 8) compose(&BufA[(size_t)(threadIdx.x - 8*BTILE) * 13], cur2, cur2);

        // broadcast row g-1 (same-address LDS reads across j: free broadcast)
        #pragma unroll
        for (int k = 0; k < 12; ++k) rowB[k] = cur2[k];
        __syncthreads();
        float E[12];
        #pragma unroll
        for (int k = 0; k < 12; ++k)
            E[k] = BufB[(size_t)((g - 1) * BTILE + bsub) * 13 + k];

        if (j == 0) {
            #pragma unroll
            for (int k = 0; k < 12; ++k) G[k] = E[k];
        } else {
            compose(E, pprev, G);
        }
    }

    // ---- Transform register-held points, streaming stores ----
    #pragma unroll
    for (int q = 0; q < 3 * RPF; ++q) {
        float ox = lx[q], oy = ly[q], oz = lz[q];
        float gx = G[0]*ox + G[1]*oy + G[2]*oz + G[9];
        float gy = G[3]*ox + G[4]*oy + G[5]*oz + G[10];
        float gz = G[6]*ox + G[7]*oy + G[8]*oz + G[11];
        size_t n = (size_t)f * (3 * RPF) + q;            // scan step index
        float* dst = out + (n * BATCH + b) * 3;
        __builtin_nontemporal_store(gx, dst + 0);
        __builtin_nontemporal_store(gy, dst + 1);
        __builtin_nontemporal_store(gz, dst + 2);
    }
}

extern "C" void kernel_launch(void* const* d_in, const int* in_sizes, int n_in,
                              void* d_out, int out_size, void* d_ws, size_t ws_size,
                              hipStream_t stream) {
    const float* dih = (const float*)d_in[0];
    float* out = (float*)d_out;
    float* T = (float*)d_ws;                           // NGRP*12*BATCH floats
    int* flags = (int*)(T + (size_t)NGRP * 12 * BATCH); // NGRP*NTILE ints

    coord_onepass<<<dim3(NGRP * NTILE), dim3(GROUP * BTILE), 0, stream>>>(
        dih, T, flags, out);
    (void)ws_size; (void)n_in; (void)out_size; (void)in_sizes;
}